// Round 1
// baseline (1056.402 us; speedup 1.0000x reference)
//
#include <hip/hip_runtime.h>
#include <math.h>

#define NN 768
#define KALL 1152     // 192*3 + 144*2 + 288
#define CATD 2112     // 192 + 3*96 + 96 + 1536
#define INF_ 100000.0f

__device__ __forceinline__ float4 ld4(const float* p) { return *(const float4*)p; }

// ---------------- 1. pack combined projection weights (q scaled by 0.25) ----------------
__global__ __launch_bounds__(256) void pack_kernel(
    const float* wq, const float* bq, const float* wk, const float* bk,
    const float* wv, const float* bv, const float* wqp, const float* bqp,
    const float* wkp, const float* bkp, const float* wvp, const float* bvp,
    float* Wall, float* ball) {
  int idx = blockIdx.x * 256 + threadIdx.x;
  if (idx >= 385 * KALL) return;
  int kk = idx / KALL, u = idx - kk * KALL;
  const float *w, *b; int col, dim; float sc = 1.f;
  if (u < 192)      { w = wq;  b = bq;  col = u;       dim = 192; sc = 0.25f; }
  else if (u < 384) { w = wk;  b = bk;  col = u - 192; dim = 192; }
  else if (u < 576) { w = wv;  b = bv;  col = u - 384; dim = 192; }
  else if (u < 720) { w = wqp; b = bqp; col = u - 576; dim = 144; }
  else if (u < 864) { w = wkp; b = bkp; col = u - 720; dim = 144; }
  else              { w = wvp; b = bvp; col = u - 864; dim = 288; }
  if (kk < 384) Wall[kk * KALL + u] = sc * w[kk * dim + col];
  else          ball[u] = sc * b[col];
}

// ---------------- 2. proj = s @ Wall + ball   [768 x 1152] ----------------
// grid (24,18): 32 rows x 64 cols per block; thread: 2 rows x 4 cols
__global__ __launch_bounds__(256) void proj_kernel(const float* s, const float* Wall,
                                                   const float* ball, float* proj) {
  int q0 = blockIdx.x * 32, c0 = blockIdx.y * 64;
  int tid = threadIdx.x;
  int qa = q0 + (tid >> 4) * 2, qb = qa + 1;
  int c = c0 + (tid & 15) * 4;
  const float* sa = s + qa * 384;
  const float* sb = s + qb * 384;
  const float* wp = Wall + c;
  float4 acc0 = {0, 0, 0, 0}, acc1 = {0, 0, 0, 0};
#pragma unroll 4
  for (int k = 0; k < 384; k++) {
    float4 w4 = ld4(wp + k * KALL);
    float a0 = sa[k], a1 = sb[k];
    acc0.x += a0 * w4.x; acc0.y += a0 * w4.y; acc0.z += a0 * w4.z; acc0.w += a0 * w4.w;
    acc1.x += a1 * w4.x; acc1.y += a1 * w4.y; acc1.z += a1 * w4.z; acc1.w += a1 * w4.w;
  }
  float4 b4 = ld4(ball + c);
  acc0.x += b4.x; acc0.y += b4.y; acc0.z += b4.z; acc0.w += b4.w;
  acc1.x += b4.x; acc1.y += b4.y; acc1.z += b4.z; acc1.w += b4.w;
  *(float4*)(proj + (size_t)qa * KALL + c) = acc0;
  *(float4*)(proj + (size_t)qb * KALL + c) = acc1;
}

// ---------------- 3. rigid-transform points + q2/k2 ----------------
// proj point layout per row: qp at 576 + h*12 + cdim*4 + p ; kp at 720 ; vp at 864 + h*24 + cdim*8 + p
__global__ __launch_bounds__(256) void points_kernel(const float* proj, const float* rot,
                                                     const float* trans, float* qpts, float* kpts,
                                                     float* vpts, float* q2, float* k2) {
  int n = blockIdx.x, tid = threadIdx.x;
  __shared__ float sq[12], sk[12];
  if (tid < 12) { sq[tid] = 0.f; sk[tid] = 0.f; }
  __syncthreads();
  if (tid < 192) {
    const float* R = rot + n * 9;
    const float* T = trans + n * 3;
    const float* pr = proj + (size_t)n * KALL;
    int base, P; float* outp; int h; bool isq = false, isk = false;
    if (tid < 48)      { h = tid >> 2; int p = tid & 3; base = 576 + h * 12; P = 4;
                         outp = qpts + n * 144 + h * 12 + p * 3; base += p; isq = true; }
    else if (tid < 96) { int i = tid - 48; h = i >> 2; int p = i & 3; base = 720 + h * 12; P = 4;
                         outp = kpts + n * 144 + h * 12 + p * 3; base += p; isk = true; }
    else               { int i = tid - 96; h = i >> 3; int p = i & 7; base = 864 + h * 24; P = 8;
                         outp = vpts + n * 288 + h * 24 + p * 3; base += p; }
    float l0 = pr[base], l1 = pr[base + P], l2 = pr[base + 2 * P];
    float g0 = R[0] * l0 + R[1] * l1 + R[2] * l2 + T[0];
    float g1 = R[3] * l0 + R[4] * l1 + R[5] * l2 + T[1];
    float g2 = R[6] * l0 + R[7] * l1 + R[8] * l2 + T[2];
    outp[0] = g0; outp[1] = g1; outp[2] = g2;
    float ns = g0 * g0 + g1 * g1 + g2 * g2;
    if (isq) atomicAdd(&sq[h], ns);
    else if (isk) atomicAdd(&sk[h], ns);
  }
  __syncthreads();
  if (tid < 12) { q2[n * 12 + tid] = sq[tid]; k2[n * 12 + tid] = sk[tid]; }
}

// ---------------- 4. bias[q][h][k] = z[q,k,:] . w_b[:,h] + b_b[h] ----------------
// grid (768, 6); block: 128 k x 2 h-groups (6 h each)
__global__ __launch_bounds__(256) void bias_kernel(const float* z, const float* wb,
                                                   const float* bb, float* abuf) {
  int q = blockIdx.x, k0 = blockIdx.y * 128;
  int tid = threadIdx.x;
  __shared__ float wsm[12 * 128];
  __shared__ float bbs[12];
  for (int i = tid; i < 1536; i += 256) { int hh = i >> 7, c = i & 127; wsm[i] = wb[c * 12 + hh]; }
  if (tid < 12) bbs[tid] = bb[tid];
  __syncthreads();
  int kl = tid & 127, h0 = tid >> 7;
  const float* zp = z + (size_t)(q * NN + k0 + kl) * 128;
  float acc[6] = {0, 0, 0, 0, 0, 0};
  for (int c4 = 0; c4 < 128; c4 += 4) {
    float4 z4 = ld4(zp + c4);
    const float zz[4] = {z4.x, z4.y, z4.z, z4.w};
#pragma unroll
    for (int cc = 0; cc < 4; cc++) {
      float zv = zz[cc];
#pragma unroll
      for (int j = 0; j < 6; j++) acc[j] += zv * wsm[(h0 + 2 * j) * 128 + c4 + cc];
    }
  }
#pragma unroll
  for (int j = 0; j < 6; j++) {
    int hh = h0 + 2 * j;
    abuf[((size_t)q * 12 + hh) * NN + k0 + kl] = acc[j] + bbs[hh];
  }
}

// ---------------- 5. logits + softmax (in-place over abuf) ----------------
// grid (96, 12): 8 q x 1 head per block; 256 threads, 3 k each
__global__ __launch_bounds__(256) void softmax_kernel(const float* proj, const float* qpts,
                                                      const float* kpts, const float* q2,
                                                      const float* k2, const float* mask,
                                                      const float* hw, float* abuf) {
  int q0 = blockIdx.x * 8, h = blockIdx.y;
  int tid = threadIdx.x;
  __shared__ float qw[8][16], qp[8][12], q2s[8], mq[8], red[4][8], row[8], pws;
  if (tid < 128) qw[tid >> 4][tid & 15] = proj[(size_t)(q0 + (tid >> 4)) * KALL + h * 16 + (tid & 15)];
  else if (tid < 224) { int i = tid - 128; qp[i / 12][i % 12] = qpts[(q0 + i / 12) * 144 + h * 12 + i % 12]; }
  else if (tid < 232) q2s[tid - 224] = q2[(q0 + tid - 224) * 12 + h];
  else if (tid < 240) mq[tid - 232] = mask[q0 + tid - 232];
  else if (tid == 240) {
    float x = hw[h];
    pws = 0.23570226039551584f * (fmaxf(x, 0.f) + log1pf(__expf(-fabsf(x))));
  }
  __syncthreads();

  float L[3][8];
#pragma unroll
  for (int i = 0; i < 3; i++) {
    int kk = i * 256 + tid;
    float kw[16], kp[12];
    const float* kwp = proj + (size_t)kk * KALL + 192 + h * 16;
    *(float4*)(kw) = ld4(kwp); *(float4*)(kw + 4) = ld4(kwp + 4);
    *(float4*)(kw + 8) = ld4(kwp + 8); *(float4*)(kw + 12) = ld4(kwp + 12);
    const float* kpp = kpts + (size_t)kk * 144 + h * 12;
    *(float4*)(kp) = ld4(kpp); *(float4*)(kp + 4) = ld4(kpp + 4); *(float4*)(kp + 8) = ld4(kpp + 8);
    float k2v = k2[kk * 12 + h];
    float mk = mask[kk];
#pragma unroll
    for (int q = 0; q < 8; q++) {
      float d = 0.f, dp = 0.f;
#pragma unroll
      for (int j = 0; j < 16; j++) d += qw[q][j] * kw[j];
#pragma unroll
      for (int j = 0; j < 12; j++) dp += qp[q][j] * kp[j];
      float bias = abuf[((size_t)(q0 + q) * 12 + h) * NN + kk];
      float val = bias + d - 0.5f * pws * (q2s[q] + k2v - 2.f * dp) + INF_ * (mq[q] * mk - 1.f);
      L[i][q] = val * 0.5773502691896258f;
    }
  }
  // block max per q-row
  float m[8];
#pragma unroll
  for (int q = 0; q < 8; q++) m[q] = fmaxf(fmaxf(L[0][q], L[1][q]), L[2][q]);
#pragma unroll
  for (int d = 1; d < 64; d <<= 1)
#pragma unroll
    for (int q = 0; q < 8; q++) m[q] = fmaxf(m[q], __shfl_xor(m[q], d, 64));
  int wv = tid >> 6;
  if ((tid & 63) == 0)
    for (int q = 0; q < 8; q++) red[wv][q] = m[q];
  __syncthreads();
  if (tid < 8) row[tid] = fmaxf(fmaxf(red[0][tid], red[1][tid]), fmaxf(red[2][tid], red[3][tid]));
  __syncthreads();
  // exp + block sum per q-row
  float sm[8];
#pragma unroll
  for (int q = 0; q < 8; q++) {
    float mm = row[q];
    L[0][q] = __expf(L[0][q] - mm);
    L[1][q] = __expf(L[1][q] - mm);
    L[2][q] = __expf(L[2][q] - mm);
    sm[q] = L[0][q] + L[1][q] + L[2][q];
  }
#pragma unroll
  for (int d = 1; d < 64; d <<= 1)
#pragma unroll
    for (int q = 0; q < 8; q++) sm[q] += __shfl_xor(sm[q], d, 64);
  if ((tid & 63) == 0)
    for (int q = 0; q < 8; q++) red[wv][q] = sm[q];
  __syncthreads();
  if (tid < 8) row[tid] = 1.f / (red[0][tid] + red[1][tid] + red[2][tid] + red[3][tid]);
  __syncthreads();
#pragma unroll
  for (int q = 0; q < 8; q++) {
    float r = row[q];
    float* ap = abuf + ((size_t)(q0 + q) * 12 + h) * NN + tid;
    ap[0] = L[0][q] * r; ap[256] = L[1][q] * r; ap[512] = L[2][q] * r;
  }
}

// ---------------- 6. o_pair[q][h][c] = sum_k a[q,h,k] z[q,k,c]  -> cat cols 576.. ----------------
// grid 768 (per q); thread: c = tid&127 fixed, 6 heads
__global__ __launch_bounds__(256) void opair_kernel(const float* z, const float* abuf, float* cat) {
  int q = blockIdx.x, tid = threadIdx.x;
  int c = tid & 127, h0 = tid >> 7;
  const float* zp = z + (size_t)q * NN * 128 + c;
  const float* ap = abuf + (size_t)q * 12 * NN;
  float acc[6] = {0, 0, 0, 0, 0, 0};
  for (int k4 = 0; k4 < NN; k4 += 4) {
    float4 av[6];
#pragma unroll
    for (int j = 0; j < 6; j++) av[j] = ld4(ap + (h0 + 2 * j) * NN + k4);
#pragma unroll
    for (int kk = 0; kk < 4; kk++) {
      float zv = zp[(size_t)(k4 + kk) * 128];
      const float* avf;
#pragma unroll
      for (int j = 0; j < 6; j++) {
        avf = (const float*)&av[j];
        acc[j] += zv * avf[kk];
      }
    }
  }
#pragma unroll
  for (int j = 0; j < 6; j++)
    cat[(size_t)q * CATD + 576 + (h0 + 2 * j) * 128 + c] = acc[j];
}

// ---------------- 7. o + o_pt (inverse rigid + norm) -> cat cols 0..576 ----------------
// grid (12, 24): head h, 32 q per block; thread: q=tid>>3, jb=tid&7 -> 5 outputs
__global__ __launch_bounds__(256) void ov_kernel(const float* proj, const float* vpts,
                                                 const float* abuf, const float* rot,
                                                 const float* trans, float* cat) {
  int h = blockIdx.x, q0 = blockIdx.y * 32;
  int tid = threadIdx.x;
  int qg = tid >> 3, jb = tid & 7;
  int q = q0 + qg;
  const float* ap = abuf + ((size_t)q * 12 + h) * NN;
  const float* vp = proj + 384 + h * 16;   // + k*KALL
  const float* vpp = vpts + h * 24;        // + k*288
  float acc[5] = {0, 0, 0, 0, 0};
  for (int k = 0; k < NN; k += 4) {
    float4 a4 = ld4(ap + k);
    const float af[4] = {a4.x, a4.y, a4.z, a4.w};
#pragma unroll
    for (int kk = 0; kk < 4; kk++) {
      float av = af[kk];
      size_t kr = k + kk;
      acc[0] += av * vp[kr * KALL + jb];
      acc[1] += av * vp[kr * KALL + jb + 8];
      acc[2] += av * vpp[kr * 288 + jb];
      acc[3] += av * vpp[kr * 288 + jb + 8];
      acc[4] += av * vpp[kr * 288 + jb + 16];
    }
  }
  float* cq = cat + (size_t)q * CATD;
  cq[h * 16 + jb] = acc[0];
  cq[h * 16 + jb + 8] = acc[1];
  __shared__ float g[32][24];
  g[qg][jb] = acc[2]; g[qg][jb + 8] = acc[3]; g[qg][jb + 16] = acc[4];
  __syncthreads();
  int ql = tid >> 3, p = tid & 7;
  int qq = q0 + ql;
  float gx = g[ql][p * 3], gy = g[ql][p * 3 + 1], gz = g[ql][p * 3 + 2];
  const float* R = rot + qq * 9;
  const float* T = trans + qq * 3;
  float dx = gx - T[0], dy = gy - T[1], dz = gz - T[2];
  float lx = R[0] * dx + R[3] * dy + R[6] * dz;  // R^T
  float ly = R[1] * dx + R[4] * dy + R[7] * dz;
  float lz = R[2] * dx + R[5] * dy + R[8] * dz;
  float nrm = sqrtf(lx * lx + ly * ly + lz * lz + 1e-8f);
  int hp = h * 8 + p;
  float* co = cat + (size_t)qq * CATD;
  co[192 + hp] = lx; co[288 + hp] = ly; co[384 + hp] = lz; co[480 + hp] = nrm;
}

// ---------------- 8. out = cat @ w_o + b_o ----------------
// grid (48, 6): 16 q x 64 c; thread: 1 q x 4 c
__global__ __launch_bounds__(256) void out_kernel(const float* cat, const float* wo,
                                                  const float* bo, float* out) {
  int q0 = blockIdx.x * 16, c0 = blockIdx.y * 64;
  int tid = threadIdx.x;
  int q = q0 + (tid >> 4);
  int c = c0 + (tid & 15) * 4;
  const float* cp = cat + (size_t)q * CATD;
  const float* wp = wo + c;
  float4 acc = {0, 0, 0, 0};
#pragma unroll 4
  for (int k = 0; k < CATD; k++) {
    float a = cp[k];
    float4 w4 = ld4(wp + (size_t)k * 384);
    acc.x += a * w4.x; acc.y += a * w4.y; acc.z += a * w4.z; acc.w += a * w4.w;
  }
  float4 b4 = ld4(bo + c);
  acc.x += b4.x; acc.y += b4.y; acc.z += b4.z; acc.w += b4.w;
  *(float4*)(out + (size_t)q * 384 + c) = acc;
}

extern "C" void kernel_launch(void* const* d_in, const int* in_sizes, int n_in,
                              void* d_out, int out_size, void* d_ws, size_t ws_size,
                              hipStream_t stream) {
  const float* s     = (const float*)d_in[0];
  const float* z     = (const float*)d_in[1];
  const float* rot   = (const float*)d_in[2];
  const float* trans = (const float*)d_in[3];
  const float* mask  = (const float*)d_in[4];
  const float* wq    = (const float*)d_in[5];
  const float* bq    = (const float*)d_in[6];
  const float* wk    = (const float*)d_in[7];
  const float* bk    = (const float*)d_in[8];
  const float* wv    = (const float*)d_in[9];
  const float* bv    = (const float*)d_in[10];
  const float* wqp   = (const float*)d_in[11];
  const float* bqp   = (const float*)d_in[12];
  const float* wkp   = (const float*)d_in[13];
  const float* bkp   = (const float*)d_in[14];
  const float* wvp   = (const float*)d_in[15];
  const float* bvp   = (const float*)d_in[16];
  const float* wb    = (const float*)d_in[17];
  const float* bb    = (const float*)d_in[18];
  const float* hw    = (const float*)d_in[19];
  const float* wo    = (const float*)d_in[20];
  const float* bo    = (const float*)d_in[21];
  float* out = (float*)d_out;

  float* ws = (float*)d_ws;
  float* proj  = ws;                       // 768*1152 = 884736
  float* Wall  = proj + 884736;            // 384*1152 = 442368
  float* ball  = Wall + 442368;            // 1152
  float* qpts  = ball + 1152;              // 768*144
  float* kpts  = qpts + 110592;            // 768*144
  float* vpts  = kpts + 110592;            // 768*288
  float* q2    = vpts + 221184;            // 768*12
  float* k2    = q2 + 9216;                // 768*12
  float* abuf  = k2 + 9216;                // 768*12*768 = 7077888
  float* cat   = abuf + 7077888;           // 768*2112 = 1622016

  pack_kernel<<<dim3((385 * KALL + 255) / 256), 256, 0, stream>>>(
      wq, bq, wk, bk, wv, bv, wqp, bqp, wkp, bkp, wvp, bvp, Wall, ball);
  proj_kernel<<<dim3(24, 18), 256, 0, stream>>>(s, Wall, ball, proj);
  points_kernel<<<dim3(768), 256, 0, stream>>>(proj, rot, trans, qpts, kpts, vpts, q2, k2);
  bias_kernel<<<dim3(768, 6), 256, 0, stream>>>(z, wb, bb, abuf);
  softmax_kernel<<<dim3(96, 12), 256, 0, stream>>>(proj, qpts, kpts, q2, k2, mask, hw, abuf);
  opair_kernel<<<dim3(768), 256, 0, stream>>>(z, abuf, cat);
  ov_kernel<<<dim3(12, 24), 256, 0, stream>>>(proj, vpts, abuf, rot, trans, cat);
  out_kernel<<<dim3(48, 6), 256, 0, stream>>>(cat, wo, bo, out);
}

// Round 2
// 929.798 us; speedup vs baseline: 1.1362x; 1.1362x over previous
//
#include <hip/hip_runtime.h>
#include <math.h>

#define NN 768
#define KALL 1152     // 192*3 + 144*2 + 288
#define CATD 2112     // 192 + 3*96 + 96 + 1536
#define INF_ 100000.0f

__device__ __forceinline__ float4 ld4(const float* p) { return *(const float4*)p; }

// ---------------- 1. pack combined projection weights (q scaled by 0.25) ----------------
__global__ __launch_bounds__(256) void pack_kernel(
    const float* wq, const float* bq, const float* wk, const float* bk,
    const float* wv, const float* bv, const float* wqp, const float* bqp,
    const float* wkp, const float* bkp, const float* wvp, const float* bvp,
    float* Wall, float* ball) {
  int idx = blockIdx.x * 256 + threadIdx.x;
  if (idx >= 385 * KALL) return;
  int kk = idx / KALL, u = idx - kk * KALL;
  const float *w, *b; int col, dim; float sc = 1.f;
  if (u < 192)      { w = wq;  b = bq;  col = u;       dim = 192; sc = 0.25f; }
  else if (u < 384) { w = wk;  b = bk;  col = u - 192; dim = 192; }
  else if (u < 576) { w = wv;  b = bv;  col = u - 384; dim = 192; }
  else if (u < 720) { w = wqp; b = bqp; col = u - 576; dim = 144; }
  else if (u < 864) { w = wkp; b = bkp; col = u - 720; dim = 144; }
  else              { w = wvp; b = bvp; col = u - 864; dim = 288; }
  if (kk < 384) Wall[kk * KALL + u] = sc * w[kk * dim + col];
  else          ball[u] = sc * b[col];
}

// ---------------- 2. proj = s @ Wall + ball   [768 x 1152] ----------------
__global__ __launch_bounds__(256) void proj_kernel(const float* s, const float* Wall,
                                                   const float* ball, float* proj) {
  int q0 = blockIdx.x * 32, c0 = blockIdx.y * 64;
  int tid = threadIdx.x;
  int qa = q0 + (tid >> 4) * 2, qb = qa + 1;
  int c = c0 + (tid & 15) * 4;
  const float* sa = s + qa * 384;
  const float* sb = s + qb * 384;
  const float* wp = Wall + c;
  float4 acc0 = {0, 0, 0, 0}, acc1 = {0, 0, 0, 0};
#pragma unroll 4
  for (int k = 0; k < 384; k++) {
    float4 w4 = ld4(wp + k * KALL);
    float a0 = sa[k], a1 = sb[k];
    acc0.x += a0 * w4.x; acc0.y += a0 * w4.y; acc0.z += a0 * w4.z; acc0.w += a0 * w4.w;
    acc1.x += a1 * w4.x; acc1.y += a1 * w4.y; acc1.z += a1 * w4.z; acc1.w += a1 * w4.w;
  }
  float4 b4 = ld4(ball + c);
  acc0.x += b4.x; acc0.y += b4.y; acc0.z += b4.z; acc0.w += b4.w;
  acc1.x += b4.x; acc1.y += b4.y; acc1.z += b4.z; acc1.w += b4.w;
  *(float4*)(proj + (size_t)qa * KALL + c) = acc0;
  *(float4*)(proj + (size_t)qb * KALL + c) = acc1;
}

// ---------------- 3. rigid-transform points + q2/k2 ----------------
__global__ __launch_bounds__(256) void points_kernel(const float* proj, const float* rot,
                                                     const float* trans, float* qpts, float* kpts,
                                                     float* vpts, float* q2, float* k2) {
  int n = blockIdx.x, tid = threadIdx.x;
  __shared__ float sq[12], sk[12];
  if (tid < 12) { sq[tid] = 0.f; sk[tid] = 0.f; }
  __syncthreads();
  if (tid < 192) {
    const float* R = rot + n * 9;
    const float* T = trans + n * 3;
    const float* pr = proj + (size_t)n * KALL;
    int base, P; float* outp; int h; bool isq = false, isk = false;
    if (tid < 48)      { h = tid >> 2; int p = tid & 3; base = 576 + h * 12; P = 4;
                         outp = qpts + n * 144 + h * 12 + p * 3; base += p; isq = true; }
    else if (tid < 96) { int i = tid - 48; h = i >> 2; int p = i & 3; base = 720 + h * 12; P = 4;
                         outp = kpts + n * 144 + h * 12 + p * 3; base += p; isk = true; }
    else               { int i = tid - 96; h = i >> 3; int p = i & 7; base = 864 + h * 24; P = 8;
                         outp = vpts + n * 288 + h * 24 + p * 3; base += p; }
    float l0 = pr[base], l1 = pr[base + P], l2 = pr[base + 2 * P];
    float g0 = R[0] * l0 + R[1] * l1 + R[2] * l2 + T[0];
    float g1 = R[3] * l0 + R[4] * l1 + R[5] * l2 + T[1];
    float g2 = R[6] * l0 + R[7] * l1 + R[8] * l2 + T[2];
    outp[0] = g0; outp[1] = g1; outp[2] = g2;
    float ns = g0 * g0 + g1 * g1 + g2 * g2;
    if (isq) atomicAdd(&sq[h], ns);
    else if (isk) atomicAdd(&sk[h], ns);
  }
  __syncthreads();
  if (tid < 12) { q2[n * 12 + tid] = sq[tid]; k2[n * 12 + tid] = sk[tid]; }
}

// ---------------- 4. bias[q][h][k] = z[q,k,:] . w_b[:,h] + b_b[h] ----------------
__global__ __launch_bounds__(256) void bias_kernel(const float* z, const float* wb,
                                                   const float* bb, float* abuf) {
  int q = blockIdx.x, k0 = blockIdx.y * 128;
  int tid = threadIdx.x;
  __shared__ float wsm[12 * 128];
  __shared__ float bbs[12];
  for (int i = tid; i < 1536; i += 256) { int hh = i >> 7, c = i & 127; wsm[i] = wb[c * 12 + hh]; }
  if (tid < 12) bbs[tid] = bb[tid];
  __syncthreads();
  int kl = tid & 127, h0 = tid >> 7;
  const float* zp = z + (size_t)(q * NN + k0 + kl) * 128;
  float acc[6] = {0, 0, 0, 0, 0, 0};
  for (int c4 = 0; c4 < 128; c4 += 4) {
    float4 z4 = ld4(zp + c4);
    const float zz[4] = {z4.x, z4.y, z4.z, z4.w};
#pragma unroll
    for (int cc = 0; cc < 4; cc++) {
      float zv = zz[cc];
#pragma unroll
      for (int j = 0; j < 6; j++) acc[j] += zv * wsm[(h0 + 2 * j) * 128 + c4 + cc];
    }
  }
#pragma unroll
  for (int j = 0; j < 6; j++) {
    int hh = h0 + 2 * j;
    abuf[((size_t)q * 12 + hh) * NN + k0 + kl] = acc[j] + bbs[hh];
  }
}

// ---------------- 5. logits + softmax (in-place over abuf) ----------------
__global__ __launch_bounds__(256) void softmax_kernel(const float* proj, const float* qpts,
                                                      const float* kpts, const float* q2,
                                                      const float* k2, const float* mask,
                                                      const float* hw, float* abuf) {
  int q0 = blockIdx.x * 8, h = blockIdx.y;
  int tid = threadIdx.x;
  __shared__ float qw[8][16], qp[8][12], q2s[8], mq[8], red[4][8], row[8], pws;
  if (tid < 128) qw[tid >> 4][tid & 15] = proj[(size_t)(q0 + (tid >> 4)) * KALL + h * 16 + (tid & 15)];
  else if (tid < 224) { int i = tid - 128; qp[i / 12][i % 12] = qpts[(q0 + i / 12) * 144 + h * 12 + i % 12]; }
  else if (tid < 232) q2s[tid - 224] = q2[(q0 + tid - 224) * 12 + h];
  else if (tid < 240) mq[tid - 232] = mask[q0 + tid - 232];
  else if (tid == 240) {
    float x = hw[h];
    pws = 0.23570226039551584f * (fmaxf(x, 0.f) + log1pf(__expf(-fabsf(x))));
  }
  __syncthreads();

  float L[3][8];
#pragma unroll
  for (int i = 0; i < 3; i++) {
    int kk = i * 256 + tid;
    float kw[16], kp[12];
    const float* kwp = proj + (size_t)kk * KALL + 192 + h * 16;
    *(float4*)(kw) = ld4(kwp); *(float4*)(kw + 4) = ld4(kwp + 4);
    *(float4*)(kw + 8) = ld4(kwp + 8); *(float4*)(kw + 12) = ld4(kwp + 12);
    const float* kpp = kpts + (size_t)kk * 144 + h * 12;
    *(float4*)(kp) = ld4(kpp); *(float4*)(kp + 4) = ld4(kpp + 4); *(float4*)(kp + 8) = ld4(kpp + 8);
    float k2v = k2[kk * 12 + h];
    float mk = mask[kk];
#pragma unroll
    for (int q = 0; q < 8; q++) {
      float d = 0.f, dp = 0.f;
#pragma unroll
      for (int j = 0; j < 16; j++) d += qw[q][j] * kw[j];
#pragma unroll
      for (int j = 0; j < 12; j++) dp += qp[q][j] * kp[j];
      float bias = abuf[((size_t)(q0 + q) * 12 + h) * NN + kk];
      float val = bias + d - 0.5f * pws * (q2s[q] + k2v - 2.f * dp) + INF_ * (mq[q] * mk - 1.f);
      L[i][q] = val * 0.5773502691896258f;
    }
  }
  float m[8];
#pragma unroll
  for (int q = 0; q < 8; q++) m[q] = fmaxf(fmaxf(L[0][q], L[1][q]), L[2][q]);
#pragma unroll
  for (int d = 1; d < 64; d <<= 1)
#pragma unroll
    for (int q = 0; q < 8; q++) m[q] = fmaxf(m[q], __shfl_xor(m[q], d, 64));
  int wv = tid >> 6;
  if ((tid & 63) == 0)
    for (int q = 0; q < 8; q++) red[wv][q] = m[q];
  __syncthreads();
  if (tid < 8) row[tid] = fmaxf(fmaxf(red[0][tid], red[1][tid]), fmaxf(red[2][tid], red[3][tid]));
  __syncthreads();
  float sm[8];
#pragma unroll
  for (int q = 0; q < 8; q++) {
    float mm = row[q];
    L[0][q] = __expf(L[0][q] - mm);
    L[1][q] = __expf(L[1][q] - mm);
    L[2][q] = __expf(L[2][q] - mm);
    sm[q] = L[0][q] + L[1][q] + L[2][q];
  }
#pragma unroll
  for (int d = 1; d < 64; d <<= 1)
#pragma unroll
    for (int q = 0; q < 8; q++) sm[q] += __shfl_xor(sm[q], d, 64);
  if ((tid & 63) == 0)
    for (int q = 0; q < 8; q++) red[wv][q] = sm[q];
  __syncthreads();
  if (tid < 8) row[tid] = 1.f / (red[0][tid] + red[1][tid] + red[2][tid] + red[3][tid]);
  __syncthreads();
#pragma unroll
  for (int q = 0; q < 8; q++) {
    float r = row[q];
    float* ap = abuf + ((size_t)(q0 + q) * 12 + h) * NN + tid;
    ap[0] = L[0][q] * r; ap[256] = L[1][q] * r; ap[512] = L[2][q] * r;
  }
}

// ---------------- 6. o_pair[q][h][c] = sum_k a[q,h,k] z[q,k,c]  -> cat cols 576.. ----------------
__global__ __launch_bounds__(256) void opair_kernel(const float* z, const float* abuf, float* cat) {
  int q = blockIdx.x, tid = threadIdx.x;
  int c = tid & 127, h0 = tid >> 7;
  const float* zp = z + (size_t)q * NN * 128 + c;
  const float* ap = abuf + (size_t)q * 12 * NN;
  float acc[6] = {0, 0, 0, 0, 0, 0};
  for (int k4 = 0; k4 < NN; k4 += 4) {
    float4 av[6];
#pragma unroll
    for (int j = 0; j < 6; j++) av[j] = ld4(ap + (h0 + 2 * j) * NN + k4);
#pragma unroll
    for (int kk = 0; kk < 4; kk++) {
      float zv = zp[(size_t)(k4 + kk) * 128];
      const float* avf;
#pragma unroll
      for (int j = 0; j < 6; j++) {
        avf = (const float*)&av[j];
        acc[j] += zv * avf[kk];
      }
    }
  }
#pragma unroll
  for (int j = 0; j < 6; j++)
    cat[(size_t)q * CATD + 576 + (h0 + 2 * j) * 128 + c] = acc[j];
}

// ---------------- 7. o + o_pt (inverse rigid + norm) -> cat cols 0..576 ----------------
__global__ __launch_bounds__(256) void ov_kernel(const float* proj, const float* vpts,
                                                 const float* abuf, const float* rot,
                                                 const float* trans, float* cat) {
  int h = blockIdx.x, q0 = blockIdx.y * 32;
  int tid = threadIdx.x;
  int qg = tid >> 3, jb = tid & 7;
  int q = q0 + qg;
  const float* ap = abuf + ((size_t)q * 12 + h) * NN;
  const float* vp = proj + 384 + h * 16;   // + k*KALL
  const float* vpp = vpts + h * 24;        // + k*288
  float acc[5] = {0, 0, 0, 0, 0};
  for (int k = 0; k < NN; k += 4) {
    float4 a4 = ld4(ap + k);
    const float af[4] = {a4.x, a4.y, a4.z, a4.w};
#pragma unroll
    for (int kk = 0; kk < 4; kk++) {
      float av = af[kk];
      size_t kr = k + kk;
      acc[0] += av * vp[kr * KALL + jb];
      acc[1] += av * vp[kr * KALL + jb + 8];
      acc[2] += av * vpp[kr * 288 + jb];
      acc[3] += av * vpp[kr * 288 + jb + 8];
      acc[4] += av * vpp[kr * 288 + jb + 16];
    }
  }
  float* cq = cat + (size_t)q * CATD;
  cq[h * 16 + jb] = acc[0];
  cq[h * 16 + jb + 8] = acc[1];
  __shared__ float g[32][24];
  g[qg][jb] = acc[2]; g[qg][jb + 8] = acc[3]; g[qg][jb + 16] = acc[4];
  __syncthreads();
  int ql = tid >> 3, p = tid & 7;
  int qq = q0 + ql;
  float gx = g[ql][p * 3], gy = g[ql][p * 3 + 1], gz = g[ql][p * 3 + 2];
  const float* R = rot + qq * 9;
  const float* T = trans + qq * 3;
  float dx = gx - T[0], dy = gy - T[1], dz = gz - T[2];
  float lx = R[0] * dx + R[3] * dy + R[6] * dz;  // R^T
  float ly = R[1] * dx + R[4] * dy + R[7] * dz;
  float lz = R[2] * dx + R[5] * dy + R[8] * dz;
  float nrm = sqrtf(lx * lx + ly * ly + lz * lz + 1e-8f);
  int hp = h * 8 + p;
  float* co = cat + (size_t)qq * CATD;
  co[192 + hp] = lx; co[288 + hp] = ly; co[384 + hp] = lz; co[480 + hp] = nrm;
}

// ---------------- 8a. out partials: split-K GEMM  cat[768x2112] @ wo[2112x384] ----------------
// grid (48, 6, 8): 16 q x 64 c per block, K chunk = 264. 2304 blocks -> 36 waves/CU.
__global__ __launch_bounds__(256) void out_part_kernel(const float* cat, const float* wo,
                                                       float* part) {
  int q0 = blockIdx.x * 16, c0 = blockIdx.y * 64, k0 = blockIdx.z * 264;
  int tid = threadIdx.x;
  int q = q0 + (tid >> 4);
  int c = c0 + (tid & 15) * 4;
  const float* cp = cat + (size_t)q * CATD + k0;
  const float* wp = wo + (size_t)k0 * 384 + c;
  float4 acc = {0, 0, 0, 0};
#pragma unroll 8
  for (int k = 0; k < 264; k++) {
    float a = cp[k];
    float4 w4 = ld4(wp + (size_t)k * 384);
    acc.x += a * w4.x; acc.y += a * w4.y; acc.z += a * w4.z; acc.w += a * w4.w;
  }
  *(float4*)(part + ((size_t)blockIdx.z * 768 + q) * 384 + c) = acc;
}

// ---------------- 8b. out = sum_j part[j] + b_o ----------------
// 768*384/4 = 73728 float4 outputs -> grid 288 x 256
__global__ __launch_bounds__(256) void out_reduce_kernel(const float* part, const float* bo,
                                                         float* out) {
  int idx = blockIdx.x * 256 + threadIdx.x;  // float4 index over [768*96]
  int q = idx / 96, cg = idx - q * 96;
  int c = cg * 4;
  float4 acc = ld4(bo + c);
#pragma unroll
  for (int j = 0; j < 8; j++) {
    float4 p = ld4(part + ((size_t)j * 768 + q) * 384 + c);
    acc.x += p.x; acc.y += p.y; acc.z += p.z; acc.w += p.w;
  }
  *(float4*)(out + (size_t)q * 384 + c) = acc;
}

extern "C" void kernel_launch(void* const* d_in, const int* in_sizes, int n_in,
                              void* d_out, int out_size, void* d_ws, size_t ws_size,
                              hipStream_t stream) {
  const float* s     = (const float*)d_in[0];
  const float* z     = (const float*)d_in[1];
  const float* rot   = (const float*)d_in[2];
  const float* trans = (const float*)d_in[3];
  const float* mask  = (const float*)d_in[4];
  const float* wq    = (const float*)d_in[5];
  const float* bq    = (const float*)d_in[6];
  const float* wk    = (const float*)d_in[7];
  const float* bk    = (const float*)d_in[8];
  const float* wv    = (const float*)d_in[9];
  const float* bv    = (const float*)d_in[10];
  const float* wqp   = (const float*)d_in[11];
  const float* bqp   = (const float*)d_in[12];
  const float* wkp   = (const float*)d_in[13];
  const float* bkp   = (const float*)d_in[14];
  const float* wvp   = (const float*)d_in[15];
  const float* bvp   = (const float*)d_in[16];
  const float* wb    = (const float*)d_in[17];
  const float* bb    = (const float*)d_in[18];
  const float* hw    = (const float*)d_in[19];
  const float* wo    = (const float*)d_in[20];
  const float* bo    = (const float*)d_in[21];
  float* out = (float*)d_out;

  float* ws = (float*)d_ws;
  float* proj  = ws;                       // 768*1152
  float* Wall  = proj + 884736;            // 384*1152
  float* ball  = Wall + 442368;            // 1152
  float* qpts  = ball + 1152;              // 768*144
  float* kpts  = qpts + 110592;            // 768*144
  float* vpts  = kpts + 110592;            // 768*288
  float* q2    = vpts + 221184;            // 768*12
  float* k2    = q2 + 9216;                // 768*12
  float* abuf  = k2 + 9216;                // 768*12*768
  float* cat   = abuf + 7077888;           // 768*2112
  float* part  = cat + 1622016;            // 8*768*384 = 2359296

  pack_kernel<<<dim3((385 * KALL + 255) / 256), 256, 0, stream>>>(
      wq, bq, wk, bk, wv, bv, wqp, bqp, wkp, bkp, wvp, bvp, Wall, ball);
  proj_kernel<<<dim3(24, 18), 256, 0, stream>>>(s, Wall, ball, proj);
  points_kernel<<<dim3(768), 256, 0, stream>>>(proj, rot, trans, qpts, kpts, vpts, q2, k2);
  bias_kernel<<<dim3(768, 6), 256, 0, stream>>>(z, wb, bb, abuf);
  softmax_kernel<<<dim3(96, 12), 256, 0, stream>>>(proj, qpts, kpts, q2, k2, mask, hw, abuf);
  opair_kernel<<<dim3(768), 256, 0, stream>>>(z, abuf, cat);
  ov_kernel<<<dim3(12, 24), 256, 0, stream>>>(proj, vpts, abuf, rot, trans, cat);
  out_part_kernel<<<dim3(48, 6, 8), 256, 0, stream>>>(cat, wo, part);
  out_reduce_kernel<<<dim3(288), 256, 0, stream>>>(part, bo, out);
}